// Round 9
// baseline (188.616 us; speedup 1.0000x reference)
//
#include <hip/hip_runtime.h>

typedef _Float16 half8 __attribute__((ext_vector_type(8)));
typedef float floatx16 __attribute__((ext_vector_type(16)));

constexpr int C = 32, H = 512, W = 512, HW = H * W;
constexpr int TBW = 32;             // output px per block (one 32-wide column)
constexpr int TBH = 4;              // output rows per tile (1 per wave)
constexpr int NT  = 4;              // tiles marched per block -> 16 output rows
constexpr int RR  = TBH + 2;        // 6 staged input rows per tile
constexpr int PX  = TBW + 8;        // 40 staged px per row (w0-4 .. w0+35)
constexpr int PXW = 20;             // words/px: 16 x-fp16 + 2 depth(e-,e+) + 2 pad
constexpr int ROWW = PX * PXW + 4;  // 804 words; %32==4 skews row base banks

__device__ __forceinline__ unsigned pack2h(float lo, float hi) {
    unsigned a = (unsigned)__builtin_bit_cast(unsigned short, (_Float16)lo);
    unsigned b = (unsigned)__builtin_bit_cast(unsigned short, (_Float16)hi);
    return a | (b << 16);
}

// ---- weights -> per-lane fp16 A-frags for mfma_f32_32x32x16_f16.
__global__ __launch_bounds__(256) void pack_w(const float* __restrict__ weight,
                                              uint4* __restrict__ wp) {
    int j = blockIdx.x * 256 + threadIdx.x;
    if (j >= 1152) return;                       // 9 taps * 2 khalves * 64 lanes
    int lane = j & 63, kh = (j >> 6) & 1, tap = j >> 7;
    int m = lane & 31, hh = lane >> 5;
    const float* wb = weight + (size_t)(m * 32 + kh * 16 + hh * 8) * 9 + tap;
    uint4 v;
    v.x = pack2h(wb[0 * 9], wb[1 * 9]);
    v.y = pack2h(wb[2 * 9], wb[3 * 9]);
    v.z = pack2h(wb[4 * 9], wb[5 * 9]);
    v.w = pack2h(wb[6 * 9], wb[7 * 9]);
    wp[j] = v;
}

// ---- persistent marching conv: grid 1024 = exactly 4 blocks/CU, all resident.
// Block = 32-px column x 16 rows, marched as 4 tiles with LDS double-buffer.
// Per tile: issue next tile's loads -> compute current (R7 inner, verbatim)
// -> store -> barrier -> write prefetch regs to other buf -> barrier.
__global__ __launch_bounds__(256, 4) void depthconv_fused(
    const float* __restrict__ x, const float* __restrict__ depth,
    const uint4* __restrict__ wp, const float* __restrict__ bias,
    float* __restrict__ out)
{
    __shared__ __attribute__((aligned(16))) unsigned xsl[2][RR * ROWW];  // 38.6 KB

    const int bid  = blockIdx.x;
    const int band = bid & 7;                    // XCD id (round-robin dispatch)
    const int mm   = bid >> 3;                   // 0..127 within band
    const int wseg = mm & 15;                    // w-fast within band
    const int vseg = (mm >> 4) & 3;
    const int b    = (mm >> 6) & 1;
    const int w0 = wseg * TBW;
    const int h0 = band * 64 + vseg * 16;        // block owns rows h0..h0+15
    const int tid = threadIdx.x;
    const int lane = tid & 63, wid = tid >> 6;
    const int pcl = lane & 31, hh = lane >> 5;   // px-in-tile, k-subgroup

    // decode stage-unit coords once (identical for issue and publish loops)
    int uf4[4], ucp[4], urr[4]; bool uok[4];
    #pragma unroll
    for (int k = 0; k < 4; ++k) {
        int u = tid + k * 256;
        uok[k] = (u < 960);
        int uc = uok[k] ? u : 959;               // clamp decode, not address
        uf4[k] = uc % 10; int tt = uc / 10;
        ucp[k] = tt & 15; urr[k] = tt >> 4;
    }
    const int dpx = tid % PX, drr = tid / PX;    // depth unit (tid<240 publishes)

    float4 bvx[4];                               // bias regs, reused each tile
    #pragma unroll
    for (int g = 0; g < 4; ++g)
        bvx[g] = *(const float4*)(bias + g * 8 + 4 * hh);

    // ---- prologue: stage tile 0 directly into buf 0
    #pragma unroll
    for (int k = 0; k < 4; ++k) {
        if (uok[k]) {
            int h = h0 - 1 + urr[k], wst = w0 - 4 + 4 * uf4[k];
            bool valid = ((unsigned)h < (unsigned)H) && ((unsigned)wst < (unsigned)W);
            float4 va = {0.f, 0.f, 0.f, 0.f}, vb = {0.f, 0.f, 0.f, 0.f};
            if (valid) {
                const float* xb = x + ((size_t)(b * C + 2 * ucp[k])) * HW
                                    + (size_t)h * W + wst;
                va = *(const float4*)xb;
                vb = *(const float4*)(xb + HW);
            }
            int word = 4 * ((ucp[k] >> 2) ^ ((uf4[k] >> 1) & 3)) + (ucp[k] & 3);
            unsigned* dst = &xsl[0][urr[k] * ROWW + (4 * uf4[k]) * PXW + word];
            dst[0 * PXW] = pack2h(va.x, vb.x);
            dst[1 * PXW] = pack2h(va.y, vb.y);
            dst[2 * PXW] = pack2h(va.z, vb.z);
            dst[3 * PXW] = pack2h(va.w, vb.w);
        }
    }
    if (tid < RR * PX) {
        int h = h0 - 1 + drr, ww = w0 - 4 + dpx;
        bool valid = ((unsigned)h < (unsigned)H) && ((unsigned)ww < (unsigned)W);
        float d = valid ? depth[(size_t)b * HW + (size_t)h * W + ww] : 0.f;
        float2 e = valid ? make_float2(__expf(-8.3f * d), __expf(8.3f * d))
                         : make_float2(0.f, 0.f);
        *(float2*)&xsl[0][drr * ROWW + dpx * PXW + 16] = e;
    }
    __syncthreads();

    // ---- march
    #pragma unroll
    for (int t = 0; t < NT; ++t) {
        const int cb  = t & 1;
        const int h0t = h0 + 4 * t;

        // -- issue next tile's loads (clamped addrs: deep-batched, no branches)
        float4 pva[4], pvb[4]; float pd = 0.f;
        if (t < NT - 1) {
            const int h1 = h0t + 4;
            #pragma unroll
            for (int k = 0; k < 4; ++k) {
                int h = h1 - 1 + urr[k], wst = w0 - 4 + 4 * uf4[k];
                int hc = h < 0 ? 0 : (h > H - 1 ? H - 1 : h);
                int wc = wst < 0 ? 0 : (wst > W - 4 ? W - 4 : wst);
                const float* xb = x + ((size_t)(b * C + 2 * ucp[k])) * HW
                                    + (size_t)hc * W + wc;
                pva[k] = *(const float4*)xb;
                pvb[k] = *(const float4*)(xb + HW);
            }
            {
                int h = h1 - 1 + drr, ww = w0 - 4 + dpx;
                int hc = h < 0 ? 0 : (h > H - 1 ? H - 1 : h);
                int wc = ww < 0 ? 0 : (ww > W - 1 ? W - 1 : ww);
                pd = depth[(size_t)b * HW + (size_t)hc * W + wc];
            }
        }

        // -- compute tile t from buf cb (R7 inner loop, verbatim)
        floatx16 accA, accB;
        #pragma unroll
        for (int g = 0; g < 4; ++g) {
            accA[4 * g + 0] = bvx[g].x; accA[4 * g + 1] = bvx[g].y;
            accA[4 * g + 2] = bvx[g].z; accA[4 * g + 3] = bvx[g].w;
            accB[4 * g + 0] = 0.f;      accB[4 * g + 1] = 0.f;
            accB[4 * g + 2] = 0.f;      accB[4 * g + 3] = 0.f;
        }
        const float2 dc = *(const float2*)&xsl[cb][(wid + 1) * ROWW + (pcl + 4) * PXW + 16];

        #pragma unroll
        for (int ki = 0; ki < 3; ++ki) {
            const unsigned* srow = &xsl[cb][(wid + ki) * ROWW];
            const uint4* wpt = wp + (size_t)(ki * 3) * 128;
            #pragma clang loop unroll(disable)
            for (int kj = 0; kj < 3; ++kj) {
                int p = pcl + 3 + kj;
                int key = (p >> 3) & 3;
                const unsigned* rec = srow + p * PXW;
                uint4 x0 = *(const uint4*)(rec + 4 * (hh ^ key));
                uint4 x1 = *(const uint4*)(rec + 4 * ((2 + hh) ^ key));
                float2 dn = *(const float2*)(rec + 16);
                float s = fminf(dn.y * dc.x, dn.x * dc.y);   // exp(-8.3|dc-dn|)
                _Float16 hs = (_Float16)s;
                half8 sv = { hs, hs, hs, hs, hs, hs, hs, hs };
                half8 a0 = __builtin_bit_cast(half8, wpt[kj * 128 + lane]);
                half8 a1 = __builtin_bit_cast(half8, wpt[kj * 128 + 64 + lane]);
                accA = __builtin_amdgcn_mfma_f32_32x32x16_f16(
                           a0, __builtin_bit_cast(half8, x0) * sv, accA, 0, 0, 0);
                accB = __builtin_amdgcn_mfma_f32_32x32x16_f16(
                           a1, __builtin_bit_cast(half8, x1) * sv, accB, 0, 0, 0);
            }
        }

        // -- epilogue tile t
        float* op = out + (size_t)b * C * HW + (size_t)(h0t + wid) * W + w0 + pcl;
        #pragma unroll
        for (int i = 0; i < 16; ++i) {
            int ch = (i & 3) + 8 * (i >> 2) + 4 * hh;
            op[(size_t)ch * HW] = accA[i] + accB[i];
        }

        // -- publish prefetched tile into the other buffer
        if (t < NT - 1) {
            const int h1 = h0t + 4;
            __syncthreads();                     // everyone done reading buf cb^1
            #pragma unroll
            for (int k = 0; k < 4; ++k) {
                if (uok[k]) {
                    int h = h1 - 1 + urr[k], wst = w0 - 4 + 4 * uf4[k];
                    bool valid = ((unsigned)h < (unsigned)H) && ((unsigned)wst < (unsigned)W);
                    float4 A = pva[k], B = pvb[k];
                    if (!valid) { A = make_float4(0,0,0,0); B = make_float4(0,0,0,0); }
                    int word = 4 * ((ucp[k] >> 2) ^ ((uf4[k] >> 1) & 3)) + (ucp[k] & 3);
                    unsigned* dst = &xsl[cb ^ 1][urr[k] * ROWW + (4 * uf4[k]) * PXW + word];
                    dst[0 * PXW] = pack2h(A.x, B.x);
                    dst[1 * PXW] = pack2h(A.y, B.y);
                    dst[2 * PXW] = pack2h(A.z, B.z);
                    dst[3 * PXW] = pack2h(A.w, B.w);
                }
            }
            if (tid < RR * PX) {
                int h = h1 - 1 + drr, ww = w0 - 4 + dpx;
                bool valid = ((unsigned)h < (unsigned)H) && ((unsigned)ww < (unsigned)W);
                float2 e = valid ? make_float2(__expf(-8.3f * pd), __expf(8.3f * pd))
                                 : make_float2(0.f, 0.f);
                *(float2*)&xsl[cb ^ 1][drr * ROWW + dpx * PXW + 16] = e;
            }
            __syncthreads();
        }
    }
}

extern "C" void kernel_launch(void* const* d_in, const int* in_sizes, int n_in,
                              void* d_out, int out_size, void* d_ws, size_t ws_size,
                              hipStream_t stream) {
    const float* x      = (const float*)d_in[0];
    const float* depth  = (const float*)d_in[1];
    const float* weight = (const float*)d_in[2];
    const float* bias   = (const float*)d_in[3];
    float* out          = (float*)d_out;

    uint4* wpk = (uint4*)d_ws;                   // 18.4 KB, only ws user

    hipLaunchKernelGGL(pack_w, dim3(5), dim3(256), 0, stream, weight, wpk);
    // grid: 8 bands * (16 wseg * 4 vseg * 2 b) = 1024 = exactly 4 blocks/CU
    hipLaunchKernelGGL(depthconv_fused, dim3(1024), dim3(256), 0, stream,
                       x, depth, wpk, bias, out);
}

// Round 10
// 140.621 us; speedup vs baseline: 1.3413x; 1.3413x over previous
//
#include <hip/hip_runtime.h>

typedef _Float16 half8 __attribute__((ext_vector_type(8)));
typedef float floatx16 __attribute__((ext_vector_type(16)));

constexpr int C = 32, H = 512, W = 512, HW = H * W;
constexpr int TBW = 64;             // output px per block: 256-B granule-exclusive
constexpr int NSTEP = 8;            // 8 steps x 2 rows = 16 output rows per block
constexpr int PX  = TBW + 8;        // 72 staged px per row (w0-4 .. w0+67)
constexpr int PXW = 20;             // words/px: 16 x-fp16 + 2 depth(e-,e+) + 2 pad
constexpr int ROWW = PX * PXW + 4;  // 1444 words; %32==4 skews row base banks
constexpr int NSLOT = 6;            // ring: rows j, slot = j % 6

__device__ __forceinline__ unsigned pack2h(float lo, float hi) {
    unsigned a = (unsigned)__builtin_bit_cast(unsigned short, (_Float16)lo);
    unsigned b = (unsigned)__builtin_bit_cast(unsigned short, (_Float16)hi);
    return a | (b << 16);
}

// ---- weights -> per-lane fp16 A-frags for mfma_f32_32x32x16_f16.
__global__ __launch_bounds__(256) void pack_w(const float* __restrict__ weight,
                                              uint4* __restrict__ wp) {
    int j = blockIdx.x * 256 + threadIdx.x;
    if (j >= 1152) return;                       // 9 taps * 2 khalves * 64 lanes
    int lane = j & 63, kh = (j >> 6) & 1, tap = j >> 7;
    int m = lane & 31, hh = lane >> 5;
    const float* wb = weight + (size_t)(m * 32 + kh * 16 + hh * 8) * 9 + tap;
    uint4 v;
    v.x = pack2h(wb[0 * 9], wb[1 * 9]);
    v.y = pack2h(wb[2 * 9], wb[3 * 9]);
    v.z = pack2h(wb[4 * 9], wb[5 * 9]);
    v.w = pack2h(wb[6 * 9], wb[7 * 9]);
    wp[j] = v;
}

// ---- granule-exclusive marching conv. Block = 64-px column x 16 rows,
// 8 steps x 2 rows, ring-of-6 LDS row window, each input row staged ONCE.
// Per step: issue next-2-rows loads | compute 2 rows | store | bar | publish | bar.
// TBW=64 -> out 256-B granules block-exclusive: no RFO (R9's failure mode).
__global__ __launch_bounds__(256, 2) void depthconv_fused(
    const float* __restrict__ x, const float* __restrict__ depth,
    const uint4* __restrict__ wp, const float* __restrict__ bias,
    float* __restrict__ out)
{
    __shared__ __attribute__((aligned(16))) unsigned xsl[NSLOT * ROWW];  // 34.7 KB

    const int bid  = blockIdx.x;
    const int band = bid & 7;                    // XCD id (round-robin dispatch)
    const int mm   = bid >> 3;                   // 0..63 within band
    const int wseg = mm & 7;                     // w-fast within band
    const int vsub = (mm >> 3) & 3;
    const int b    = (mm >> 5) & 1;
    const int w0 = wseg * TBW;
    const int h0 = band * 64 + vsub * 16;        // block owns rows h0..h0+15
    const int tid = threadIdx.x;
    const int lane = tid & 63, wid = tid >> 6;
    const int ph = wid & 1, rsel = wid >> 1;     // px-half, row-within-step
    const int pcl = ph * 32 + (lane & 31);       // tile-local output px 0..63
    const int hh = lane >> 5;                    // k-subgroup

    // A-frags: 72 VGPRs live across the kernel (off the MFMA dependent path)
    half8 afA[9], afB[9];
    #pragma unroll
    for (int t = 0; t < 9; ++t) {
        afA[t] = __builtin_bit_cast(half8, wp[t * 128 + lane]);
        afB[t] = __builtin_bit_cast(half8, wp[t * 128 + 64 + lane]);
    }
    float4 bvx[4];
    #pragma unroll
    for (int g = 0; g < 4; ++g)
        bvx[g] = *(const float4*)(bias + g * 8 + 4 * hh);

    // ---- prologue: stage input rows j=0..3 (h0-1 .. h0+2) into slots 0..3
    #pragma unroll
    for (int k = 0; k < 5; ++k) {
        int u = tid + k * 256;
        if (u < 1152) {                          // 18 f4 * 16 cp * 4 r
            int f4 = u % 18, t = u / 18, cp = t & 15, r = t >> 4;
            int h = h0 - 1 + r, wst = w0 - 4 + 4 * f4;
            bool valid = ((unsigned)h < (unsigned)H) && ((unsigned)wst < (unsigned)W);
            float4 va = {0.f, 0.f, 0.f, 0.f}, vb = {0.f, 0.f, 0.f, 0.f};
            if (valid) {
                const float* xb = x + ((size_t)(b * C + 2 * cp)) * HW + (size_t)h * W + wst;
                va = *(const float4*)xb;
                vb = *(const float4*)(xb + HW);
            }
            int word = 4 * ((cp >> 2) ^ ((f4 >> 1) & 3)) + (cp & 3);
            unsigned* dst = &xsl[r * ROWW + (4 * f4) * PXW + word];
            dst[0 * PXW] = pack2h(va.x, vb.x);
            dst[1 * PXW] = pack2h(va.y, vb.y);
            dst[2 * PXW] = pack2h(va.z, vb.z);
            dst[3 * PXW] = pack2h(va.w, vb.w);
        }
    }
    #pragma unroll
    for (int k = 0; k < 2; ++k) {
        int u = tid + k * 256;
        if (u < 4 * PX) {                        // 4 rows * 72 px
            int px = u % PX, r = u / PX;
            int h = h0 - 1 + r, ww = w0 - 4 + px;
            bool valid = ((unsigned)h < (unsigned)H) && ((unsigned)ww < (unsigned)W);
            float d = valid ? depth[(size_t)b * HW + (size_t)h * W + ww] : 0.f;
            float2 e = valid ? make_float2(__expf(-8.3f * d), __expf(8.3f * d))
                             : make_float2(0.f, 0.f);
            *(float2*)&xsl[r * ROWW + px * PXW + 16] = e;
        }
    }
    __syncthreads();

    int sb = 0;                                  // slot base = (2*step) % 6
    for (int s = 0; s < NSTEP; ++s) {
        // -- issue next 2 rows' loads (j = 2s+4, 2s+5), clamped, regs only
        float4 pva[3], pvb[3]; float pd = 0.f;
        if (s < NSTEP - 1) {
            #pragma unroll
            for (int k = 0; k < 3; ++k) {
                int u = tid + k * 256;           // 576 units: 18 f4 * 16 cp * 2 rr
                bool has = (k < 2) || (tid < 64);
                int uc = has ? u : 0;
                int f4 = uc % 18, t = uc / 18, cp = t & 15, rr = t >> 4;
                int h = h0 + 2 * s + 3 + rr, wst = w0 - 4 + 4 * f4;
                int hc = h > H - 1 ? H - 1 : h;  // h >= 3 always
                int wc = wst < 0 ? 0 : (wst > W - 4 ? W - 4 : wst);
                const float* xb = x + ((size_t)(b * C + 2 * cp)) * HW
                                    + (size_t)hc * W + wc;
                pva[k] = *(const float4*)xb;
                pvb[k] = *(const float4*)(xb + HW);
            }
            if (tid < 2 * PX) {
                int px = tid % PX, rr = tid / PX;
                int h = h0 + 2 * s + 3 + rr, ww = w0 - 4 + px;
                int hc = h > H - 1 ? H - 1 : h;
                int wc = ww < 0 ? 0 : (ww > W - 1 ? W - 1 : ww);
                pd = depth[(size_t)b * HW + (size_t)hc * W + wc];
            }
        }

        // -- compute 2 output rows from slots sb..sb+3 (mod 6)
        floatx16 accA, accB;
        #pragma unroll
        for (int g = 0; g < 4; ++g) {
            accA[4 * g + 0] = bvx[g].x; accA[4 * g + 1] = bvx[g].y;
            accA[4 * g + 2] = bvx[g].z; accA[4 * g + 3] = bvx[g].w;
            accB[4 * g + 0] = 0.f;      accB[4 * g + 1] = 0.f;
            accB[4 * g + 2] = 0.f;      accB[4 * g + 3] = 0.f;
        }
        int scen = sb + 1 + rsel; if (scen >= 6) scen -= 6;
        const float2 dc = *(const float2*)&xsl[scen * ROWW + (pcl + 4) * PXW + 16];

        #pragma unroll
        for (int ki = 0; ki < 3; ++ki) {
            int sk = sb + rsel + ki; if (sk >= 6) sk -= 6;
            const unsigned* srow = &xsl[sk * ROWW];
            const uint4* wpt = wp + (size_t)(ki * 3) * 128;
            #pragma clang loop unroll(disable)
            for (int kj = 0; kj < 3; ++kj) {
                int p = pcl + 3 + kj;
                int key = (p >> 3) & 3;
                const unsigned* rec = srow + p * PXW;
                uint4 x0 = *(const uint4*)(rec + 4 * (hh ^ key));
                uint4 x1 = *(const uint4*)(rec + 4 * ((2 + hh) ^ key));
                float2 dn = *(const float2*)(rec + 16);
                float s2 = fminf(dn.y * dc.x, dn.x * dc.y);  // exp(-8.3|dc-dn|)
                _Float16 hs = (_Float16)s2;
                half8 sv = { hs, hs, hs, hs, hs, hs, hs, hs };
                half8 a0 = __builtin_bit_cast(half8, wpt[kj * 128 + lane]);
                half8 a1 = __builtin_bit_cast(half8, wpt[kj * 128 + 64 + lane]);
                accA = __builtin_amdgcn_mfma_f32_32x32x16_f16(
                           a0, __builtin_bit_cast(half8, x0) * sv, accA, 0, 0, 0);
                accB = __builtin_amdgcn_mfma_f32_32x32x16_f16(
                           a1, __builtin_bit_cast(half8, x1) * sv, accB, 0, 0, 0);
            }
        }

        // -- epilogue: output row h0+2s+rsel; 32-lane group writes 128 B;
        //    the two px-half waves complete each 256-B granule this same step
        float* op = out + (size_t)b * C * HW + (size_t)(h0 + 2 * s + rsel) * W + w0 + pcl;
        #pragma unroll
        for (int i = 0; i < 16; ++i) {
            int ch = (i & 3) + 8 * (i >> 2) + 4 * hh;
            op[(size_t)ch * HW] = accA[i] + accB[i];
        }

        // -- publish prefetched rows to slots (sb+4)%6, (sb+5)%6
        if (s < NSTEP - 1) {
            __syncthreads();                     // all waves done reading sb..sb+3
            #pragma unroll
            for (int k = 0; k < 3; ++k) {
                int u = tid + k * 256;
                bool has = (k < 2) || (tid < 64);
                if (has) {
                    int f4 = u % 18, t = u / 18, cp = t & 15, rr = t >> 4;
                    int h = h0 + 2 * s + 3 + rr, wst = w0 - 4 + 4 * f4;
                    bool valid = (h < H) && ((unsigned)wst < (unsigned)W);
                    float4 A = pva[k], B = pvb[k];
                    if (!valid) { A = make_float4(0,0,0,0); B = make_float4(0,0,0,0); }
                    int sp = sb + 4 + rr; if (sp >= 6) sp -= 6;
                    int word = 4 * ((cp >> 2) ^ ((f4 >> 1) & 3)) + (cp & 3);
                    unsigned* dst = &xsl[sp * ROWW + (4 * f4) * PXW + word];
                    dst[0 * PXW] = pack2h(A.x, B.x);
                    dst[1 * PXW] = pack2h(A.y, B.y);
                    dst[2 * PXW] = pack2h(A.z, B.z);
                    dst[3 * PXW] = pack2h(A.w, B.w);
                }
            }
            if (tid < 2 * PX) {
                int px = tid % PX, rr = tid / PX;
                int h = h0 + 2 * s + 3 + rr, ww = w0 - 4 + px;
                bool valid = (h < H) && ((unsigned)ww < (unsigned)W);
                float2 e = valid ? make_float2(__expf(-8.3f * pd), __expf(8.3f * pd))
                                 : make_float2(0.f, 0.f);
                int sp = sb + 4 + rr; if (sp >= 6) sp -= 6;
                *(float2*)&xsl[sp * ROWW + px * PXW + 16] = e;
            }
            __syncthreads();
        }
        sb += 2; if (sb >= 6) sb -= 6;
    }
}

extern "C" void kernel_launch(void* const* d_in, const int* in_sizes, int n_in,
                              void* d_out, int out_size, void* d_ws, size_t ws_size,
                              hipStream_t stream) {
    const float* x      = (const float*)d_in[0];
    const float* depth  = (const float*)d_in[1];
    const float* weight = (const float*)d_in[2];
    const float* bias   = (const float*)d_in[3];
    float* out          = (float*)d_out;

    uint4* wpk = (uint4*)d_ws;                   // 18.4 KB, only ws user

    hipLaunchKernelGGL(pack_w, dim3(5), dim3(256), 0, stream, weight, wpk);
    // grid: 8 bands * (8 wseg * 4 vsub * 2 b) = 512 = exactly 2 blocks/CU
    hipLaunchKernelGGL(depthconv_fused, dim3(512), dim3(256), 0, stream,
                       x, depth, wpk, bias, out);
}